// Round 3
// baseline (591.430 us; speedup 1.0000x reference)
//
#include <hip/hip_runtime.h>

#define B_ 256
#define M_ 512
#define N_ 256
#define K_ 16
#define ROWS 128       // rows per pass-1 block
#define NC 32          // n-chunk staged per iteration
#define NCHUNKS (N_ / NC)
#define XPAD 36        // padded LDS row stride (floats), 16B-aligned

// ---------------- Pass 1 ----------------
// grid = B_ * (M_/ROWS) = 1024 blocks, 256 threads.
// Thread t = (row r = t>>1, k-half h = t&1): computes xv[b,m,h*8..+8)
// and the h-half (by n) of the linear term.
__global__ __launch_bounds__(256, 4) void fm_pass1(
    const float* __restrict__ x, const float* __restrict__ w,
    const float* __restrict__ bias, const float* __restrict__ v,
    float* __restrict__ xv, float* __restrict__ svpart, float* __restrict__ out)
{
    __shared__ __align__(16) float vL[N_][K_];      // 16 KiB
    __shared__ __align__(16) float wL[N_];          // 1 KiB
    __shared__ __align__(16) float xT[ROWS][XPAD];  // 18 KiB

    const int t   = threadIdx.x;
    const int r   = t >> 1;         // 0..127
    const int h   = t & 1;          // k-half
    const int blk = blockIdx.x;
    const int b   = blk >> 2;       // 4 row-chunks per batch
    const int m0  = (blk & 3) * ROWS;

    // stage v (4096 floats) and w (256 floats)
    {
        const float4* v4 = (const float4*)v;
        float4* vL4 = (float4*)&vL[0][0];
        #pragma unroll
        for (int i = 0; i < 4; ++i) vL4[t + 256 * i] = v4[t + 256 * i];
        wL[t] = w[t];
    }

    const float* xb = x + ((size_t)b * M_ + m0) * N_;

    float acc0 = 0.f, acc1 = 0.f, acc2 = 0.f, acc3 = 0.f;
    float acc4 = 0.f, acc5 = 0.f, acc6 = 0.f, acc7 = 0.f;
    float lacc = 0.f;

    // staging: thread t loads row (t>>3)+32*i, 16B piece (t&7)*4 of current chunk
    // -> 8 lanes cover 128B contiguous per row (full L2 lines)
    const int lrow = t >> 3;
    const int lcol = (t & 7) * 4;
    float4 st[4];

    #pragma unroll
    for (int i = 0; i < 4; ++i)
        st[i] = *(const float4*)(xb + (size_t)(lrow + 32 * i) * N_ + 0 * NC + lcol);

    for (int nc = 0; nc < NCHUNKS; ++nc) {
        __syncthreads();
        #pragma unroll
        for (int i = 0; i < 4; ++i)
            *(float4*)&xT[lrow + 32 * i][lcol] = st[i];
        __syncthreads();

        if (nc + 1 < NCHUNKS) {
            #pragma unroll
            for (int i = 0; i < 4; ++i)
                st[i] = *(const float4*)(xb + (size_t)(lrow + 32 * i) * N_ + (nc + 1) * NC + lcol);
        }

        // linear-term ownership: n-half (n>>7) must equal h; constant per chunk
        const bool dol = ((nc >> 2) == h);

        #pragma unroll
        for (int n4 = 0; n4 < NC / 4; ++n4) {
            const float4 xq = *(const float4*)&xT[r][n4 * 4];
            #pragma unroll
            for (int j = 0; j < 4; ++j) {
                const int n = nc * NC + n4 * 4 + j;
                const float xs = (j == 0) ? xq.x : (j == 1) ? xq.y : (j == 2) ? xq.z : xq.w;
                const float4 va = *(const float4*)&vL[n][h * 8];
                const float4 vb = *(const float4*)&vL[n][h * 8 + 4];
                acc0 += xs * va.x; acc1 += xs * va.y; acc2 += xs * va.z; acc3 += xs * va.w;
                acc4 += xs * vb.x; acc5 += xs * vb.y; acc6 += xs * vb.z; acc7 += xs * vb.w;
                if (dol) lacc += xs * wL[n];
            }
        }
    }

    // xv write: lane t writes 32B at byte offset t*32 from block base -> dense
    {
        float* base = xv + ((size_t)b * M_ + m0 + r) * K_ + h * 8;
        *(float4*)base       = float4{acc0, acc1, acc2, acc3};
        *(float4*)(base + 4) = float4{acc4, acc5, acc6, acc7};
    }

    // per-wave reduce over the 32 rows in this wave (even offsets keep h-lanes apart)
    float s0 = acc0, s1 = acc1, s2 = acc2, s3 = acc3;
    float s4 = acc4, s5 = acc5, s6 = acc6, s7 = acc7;
    #pragma unroll
    for (int off = 2; off < 64; off <<= 1) {
        s0 += __shfl_xor(s0, off); s1 += __shfl_xor(s1, off);
        s2 += __shfl_xor(s2, off); s3 += __shfl_xor(s3, off);
        s4 += __shfl_xor(s4, off); s5 += __shfl_xor(s5, off);
        s6 += __shfl_xor(s6, off); s7 += __shfl_xor(s7, off);
    }
    // combine 4 wave-partials in LDS (reuse xT), then one svpart[blk][16]
    __syncthreads();                       // all compute reads of xT done
    float* red = (float*)&xT[0][0];        // [4 waves][16]
    const int wave = t >> 6;
    if ((t & 63) < 2) {                    // lanes 0 (h=0) and 1 (h=1) of each wave
        float* dst = red + wave * 16 + h * 8;
        *(float4*)dst       = float4{s0, s1, s2, s3};
        *(float4*)(dst + 4) = float4{s4, s5, s6, s7};
    }
    // linear term: combine the two n-halves per row; even lane writes
    const float lsum = lacc + __shfl_xor(lacc, 1);
    if (h == 0)
        out[(size_t)b * M_ + m0 + r] = lsum + bias[0];
    __syncthreads();
    if (t < 16)
        svpart[(size_t)blk * 16 + t] =
            red[t] + red[16 + t] + red[32 + t] + red[48 + t];
}

// ---------------- Pass 2 ----------------
// grid = B_*2 blocks, 256 threads; thread per row.
__global__ __launch_bounds__(256) void fm_pass2(
    const float* __restrict__ xv, const float* __restrict__ svpart,
    float* __restrict__ out)
{
    const int t = threadIdx.x;
    const int blk = blockIdx.x;
    const int b = blk >> 1;
    const int m = (blk & 1) * 256 + t;
    __shared__ __align__(16) float svL[16];
    if (t < 16) {
        float s = 0.f;
        #pragma unroll
        for (int j = 0; j < 4; ++j) s += svpart[((size_t)b * 4 + j) * 16 + t];
        svL[t] = s;
    }
    __syncthreads();

    const float4* xvp = (const float4*)(xv + ((size_t)b * M_ + m) * K_);
    float4 a0 = xvp[0], a1 = xvp[1], a2 = xvp[2], a3 = xvp[3];
    const float4* s4 = (const float4*)svL;
    float4 s0 = s4[0], s1 = s4[1], s2 = s4[2], s3 = s4[3];

    float rs = a0.x * s0.x + a0.y * s0.y + a0.z * s0.z + a0.w * s0.w
             + a1.x * s1.x + a1.y * s1.y + a1.z * s1.z + a1.w * s1.w
             + a2.x * s2.x + a2.y * s2.y + a2.z * s2.z + a2.w * s2.w
             + a3.x * s3.x + a3.y * s3.y + a3.z * s3.z + a3.w * s3.w;
    float dg = a0.x * a0.x + a0.y * a0.y + a0.z * a0.z + a0.w * a0.w
             + a1.x * a1.x + a1.y * a1.y + a1.z * a1.z + a1.w * a1.w
             + a2.x * a2.x + a2.y * a2.y + a2.z * a2.z + a2.w * a2.w
             + a3.x * a3.x + a3.y * a3.y + a3.z * a3.z + a3.w * a3.w;

    const size_t o = (size_t)b * M_ + m;
    out[o] = out[o] + 0.5f * (rs - dg);
}

extern "C" void kernel_launch(void* const* d_in, const int* in_sizes, int n_in,
                              void* d_out, int out_size, void* d_ws, size_t ws_size,
                              hipStream_t stream) {
    const float* x    = (const float*)d_in[0];
    const float* w    = (const float*)d_in[1];
    const float* bias = (const float*)d_in[2];
    const float* v    = (const float*)d_in[3];
    float* out = (float*)d_out;

    float* xv     = (float*)d_ws;                 // B*M*K floats = 8 MiB
    float* svpart = xv + (size_t)B_ * M_ * K_;    // 1024*16 floats = 64 KiB

    fm_pass1<<<dim3(B_ * (M_ / ROWS)), dim3(256), 0, stream>>>(x, w, bias, v, xv, svpart, out);
    fm_pass2<<<dim3(B_ * 2), dim3(256), 0, stream>>>(xv, svpart, out);
}

// Round 4
// 56.119 us; speedup vs baseline: 10.5388x; 10.5388x over previous
//
#include <hip/hip_runtime.h>

#define B_ 256
#define M_ 512
#define N_ 256
#define K_ 16
#define ROWS 256
#define NC 32
#define NCHUNKS (N_ / NC)   // 8

// direct global->LDS, 16B per lane, no VGPR staging
__device__ __forceinline__ void gload_lds16(const float* g, float* l) {
    __builtin_amdgcn_global_load_lds(
        (const __attribute__((address_space(1))) void*)g,
        (__attribute__((address_space(3))) void*)l,
        16, 0, 0);
}

// ---------------- Pass 1 ----------------
// grid = 512 blocks (2 per batch), 256 threads.
// Thread t = (rs = t>>2 in 0..63, ksub = t&3).
// Owns rows {rs, rs+64, rs+128, rs+192} of the block's 256-row tile and
// k-quad [ksub*4, ksub*4+4). Per n-quad: 8 LDS reads feed 64 FMAs.
__global__ __launch_bounds__(256) void fm_pass1(
    const float* __restrict__ x, const float* __restrict__ w,
    const float* __restrict__ bias, const float* __restrict__ v,
    float* __restrict__ xv, float* __restrict__ svpart, float* __restrict__ out)
{
    __shared__ __align__(16) float vL[N_][K_];              // 16 KiB
    __shared__ __align__(16) float wL[N_];                  // 1 KiB
    __shared__ __align__(16) unsigned char xT[ROWS * NC * 4]; // 32 KiB, swizzled

    const int t    = threadIdx.x;
    const int rs   = t >> 2;        // 0..63
    const int ksub = t & 3;
    const int blk  = blockIdx.x;
    const int b    = blk >> 1;
    const int m0   = (blk & 1) * ROWS;

    // stage v (4096 floats) and w (256 floats) once
    {
        const float4* v4 = (const float4*)v;
        float4* vL4 = (float4*)&vL[0][0];
        #pragma unroll
        for (int i = 0; i < 4; ++i) vL4[t + 256 * i] = v4[t + 256 * i];
        wL[t] = w[t];
    }

    const float* xb = x + ((size_t)b * M_ + m0) * N_;

    // staging geometry: round i covers rows 32i..32i+31, 128B per row.
    // LDS is linear (slot = lane*16B); global col-quad is pre-swizzled so that
    // reads may XOR with (row&7) and stay bank-spread.
    const int srow = t >> 3;                      // 0..31 (+32*i)
    const int sq   = (t & 7) ^ (srow & 7);        // swizzled source col-quad
    float* const ldsw = (float*)(xT + (t & 192) * 16);  // wave-uniform base (+i*4096)

    float4 a0 = {0,0,0,0}, a1 = {0,0,0,0}, a2 = {0,0,0,0}, a3 = {0,0,0,0};
    float l0 = 0.f, l1 = 0.f, l2 = 0.f, l3 = 0.f;   // linear term (ksub==0 lanes)

    const int qxb = rs & 7;
    const unsigned char* const xr0 = xT + rs * 128;

    for (int nc = 0; nc < NCHUNKS; ++nc) {
        if (nc) __syncthreads();   // all reads of previous chunk done
        #pragma unroll
        for (int i = 0; i < 8; ++i)
            gload_lds16(xb + (size_t)(srow + 32 * i) * N_ + nc * NC + sq * 4,
                        (float*)((unsigned char*)ldsw + i * 4096));
        __syncthreads();           // vmcnt drained before barrier -> tile ready

        #pragma unroll
        for (int q = 0; q < NC / 4; ++q) {
            const int qoff = ((q ^ qxb) << 4);
            const float4 x0 = *(const float4*)(xr0 +           qoff);
            const float4 x1 = *(const float4*)(xr0 +  64*128 + qoff);
            const float4 x2 = *(const float4*)(xr0 + 128*128 + qoff);
            const float4 x3 = *(const float4*)(xr0 + 192*128 + qoff);
            const int n0 = nc * NC + q * 4;
            const float4 v0 = *(const float4*)&vL[n0 + 0][ksub * 4];
            const float4 v1 = *(const float4*)&vL[n0 + 1][ksub * 4];
            const float4 v2 = *(const float4*)&vL[n0 + 2][ksub * 4];
            const float4 v3 = *(const float4*)&vL[n0 + 3][ksub * 4];

            a0.x += x0.x*v0.x + x0.y*v1.x + x0.z*v2.x + x0.w*v3.x;
            a0.y += x0.x*v0.y + x0.y*v1.y + x0.z*v2.y + x0.w*v3.y;
            a0.z += x0.x*v0.z + x0.y*v1.z + x0.z*v2.z + x0.w*v3.z;
            a0.w += x0.x*v0.w + x0.y*v1.w + x0.z*v2.w + x0.w*v3.w;

            a1.x += x1.x*v0.x + x1.y*v1.x + x1.z*v2.x + x1.w*v3.x;
            a1.y += x1.x*v0.y + x1.y*v1.y + x1.z*v2.y + x1.w*v3.y;
            a1.z += x1.x*v0.z + x1.y*v1.z + x1.z*v2.z + x1.w*v3.z;
            a1.w += x1.x*v0.w + x1.y*v1.w + x1.z*v2.w + x1.w*v3.w;

            a2.x += x2.x*v0.x + x2.y*v1.x + x2.z*v2.x + x2.w*v3.x;
            a2.y += x2.x*v0.y + x2.y*v1.y + x2.z*v2.y + x2.w*v3.y;
            a2.z += x2.x*v0.z + x2.y*v1.z + x2.z*v2.z + x2.w*v3.z;
            a2.w += x2.x*v0.w + x2.y*v1.w + x2.z*v2.w + x2.w*v3.w;

            a3.x += x3.x*v0.x + x3.y*v1.x + x3.z*v2.x + x3.w*v3.x;
            a3.y += x3.x*v0.y + x3.y*v1.y + x3.z*v2.y + x3.w*v3.y;
            a3.z += x3.x*v0.z + x3.y*v1.z + x3.z*v2.z + x3.w*v3.z;
            a3.w += x3.x*v0.w + x3.y*v1.w + x3.z*v2.w + x3.w*v3.w;

            if (ksub == 0) {
                const float4 wq = *(const float4*)&wL[n0];
                l0 += x0.x*wq.x + x0.y*wq.y + x0.z*wq.z + x0.w*wq.w;
                l1 += x1.x*wq.x + x1.y*wq.y + x1.z*wq.z + x1.w*wq.w;
                l2 += x2.x*wq.x + x2.y*wq.y + x2.z*wq.z + x2.w*wq.w;
                l3 += x3.x*wq.x + x3.y*wq.y + x3.z*wq.z + x3.w*wq.w;
            }
        }
    }

    // xv writes: 4 rows x float4, coalesced (1 KB contiguous per wave per j)
    {
        float* base = xv + ((size_t)b * M_ + m0 + rs) * K_ + ksub * 4;
        *(float4*)(base +   0 * K_) = a0;
        *(float4*)(base +  64 * K_) = a1;
        *(float4*)(base + 128 * K_) = a2;
        *(float4*)(base + 192 * K_) = a3;
    }

    // sv: local row-sum then butterfly over rowset bits (4,8,16,32)
    float4 s = {a0.x + a1.x + a2.x + a3.x,
                a0.y + a1.y + a2.y + a3.y,
                a0.z + a1.z + a2.z + a3.z,
                a0.w + a1.w + a2.w + a3.w};
    #pragma unroll
    for (int off = 4; off < 64; off <<= 1) {
        s.x += __shfl_xor(s.x, off);
        s.y += __shfl_xor(s.y, off);
        s.z += __shfl_xor(s.z, off);
        s.w += __shfl_xor(s.w, off);
    }

    __syncthreads();                       // done reading xT; reuse for reductions
    float* lred = (float*)xT;              // 256 floats
    float* red  = (float*)(xT + 1024);     // 4 waves x 16 floats
    const int wave = t >> 6;
    if ((t & 63) < 4)
        *(float4*)(red + wave * 16 + ksub * 4) = s;
    if (ksub == 0) {
        lred[rs +   0] = l0;
        lred[rs +  64] = l1;
        lred[rs + 128] = l2;
        lred[rs + 192] = l3;
    }
    __syncthreads();
    out[(size_t)b * M_ + m0 + t] = lred[t] + bias[0];
    if (t < 16)
        svpart[(size_t)blk * 16 + t] = red[t] + red[16 + t] + red[32 + t] + red[48 + t];
}

// ---------------- Pass 2 ----------------
// grid = B_*2 blocks, 256 threads; thread per row.
__global__ __launch_bounds__(256) void fm_pass2(
    const float* __restrict__ xv, const float* __restrict__ svpart,
    float* __restrict__ out)
{
    const int t = threadIdx.x;
    const int blk = blockIdx.x;
    const int b = blk >> 1;
    const int m = (blk & 1) * 256 + t;
    __shared__ __align__(16) float svL[16];
    if (t < 16)
        svL[t] = svpart[(size_t)(b * 2 + 0) * 16 + t] + svpart[(size_t)(b * 2 + 1) * 16 + t];
    __syncthreads();

    const float4* xvp = (const float4*)(xv + ((size_t)b * M_ + m) * K_);
    float4 a0 = xvp[0], a1 = xvp[1], a2 = xvp[2], a3 = xvp[3];
    const float4* s4 = (const float4*)svL;
    float4 s0 = s4[0], s1 = s4[1], s2 = s4[2], s3 = s4[3];

    float rs = a0.x * s0.x + a0.y * s0.y + a0.z * s0.z + a0.w * s0.w
             + a1.x * s1.x + a1.y * s1.y + a1.z * s1.z + a1.w * s1.w
             + a2.x * s2.x + a2.y * s2.y + a2.z * s2.z + a2.w * s2.w
             + a3.x * s3.x + a3.y * s3.y + a3.z * s3.z + a3.w * s3.w;
    float dg = a0.x * a0.x + a0.y * a0.y + a0.z * a0.z + a0.w * a0.w
             + a1.x * a1.x + a1.y * a1.y + a1.z * a1.z + a1.w * a1.w
             + a2.x * a2.x + a2.y * a2.y + a2.z * a2.z + a2.w * a2.w
             + a3.x * a3.x + a3.y * a3.y + a3.z * a3.z + a3.w * a3.w;

    const size_t o = (size_t)b * M_ + m;
    out[o] = out[o] + 0.5f * (rs - dg);
}

extern "C" void kernel_launch(void* const* d_in, const int* in_sizes, int n_in,
                              void* d_out, int out_size, void* d_ws, size_t ws_size,
                              hipStream_t stream) {
    const float* x    = (const float*)d_in[0];
    const float* w    = (const float*)d_in[1];
    const float* bias = (const float*)d_in[2];
    const float* v    = (const float*)d_in[3];
    float* out = (float*)d_out;

    float* xv     = (float*)d_ws;                 // B*M*K floats = 8 MiB
    float* svpart = xv + (size_t)B_ * M_ * K_;    // 512*16 floats

    fm_pass1<<<dim3(B_ * (M_ / ROWS)), dim3(256), 0, stream>>>(x, w, bias, v, xv, svpart, out);
    fm_pass2<<<dim3(B_ * 2), dim3(256), 0, stream>>>(xv, svpart, out);
}

// Round 5
// 45.391 us; speedup vs baseline: 13.0297x; 1.2364x over previous
//
#include <hip/hip_runtime.h>

#define B_ 256
#define M_ 512
#define N_ 256
#define K_ 16
#define ROWS 128
#define NC 32
#define NCHUNKS (N_ / NC)   // 8

// direct global->LDS, 16B per lane, no VGPR staging
__device__ __forceinline__ void gload_lds16(const float* g, float* l) {
    __builtin_amdgcn_global_load_lds(
        (const __attribute__((address_space(1))) void*)g,
        (__attribute__((address_space(3))) void*)l,
        16, 0, 0);
}

// ---------------- Pass 1 ----------------
// grid = B_*4 = 1024 blocks, 256 threads. Double-buffered x tile.
// Thread t = (rs = t>>2 in 0..63, ksub = t&3): owns rows {rs, rs+64} and
// k-quad [ksub*4, ksub*4+4).
__global__ __launch_bounds__(256) void fm_pass1(
    const float* __restrict__ x, const float* __restrict__ w,
    const float* __restrict__ bias, const float* __restrict__ v,
    float* __restrict__ xv, float* __restrict__ svpart, float* __restrict__ out)
{
    __shared__ __align__(16) float vL[N_][K_];                   // 16 KiB
    __shared__ __align__(16) float wL[N_];                       // 1 KiB
    __shared__ __align__(16) unsigned char xT[2][ROWS * NC * 4]; // 2 x 16 KiB

    const int t    = threadIdx.x;
    const int rs   = t >> 2;        // 0..63
    const int ksub = t & 3;
    const int blk  = blockIdx.x;
    const int b    = blk >> 2;      // 4 row-chunks per batch
    const int m0   = (blk & 3) * ROWS;

    // stage v (4096 floats) and w (256 floats) once
    {
        const float4* v4 = (const float4*)v;
        float4* vL4 = (float4*)&vL[0][0];
        #pragma unroll
        for (int i = 0; i < 4; ++i) vL4[t + 256 * i] = v4[t + 256 * i];
        wL[t] = w[t];
    }

    const float* xb = x + ((size_t)b * M_ + m0) * N_;

    // staging: round i covers rows 32i..32i+31, 128 B per row.
    // LDS linear (slot = lane*16B within round); source col-quad pre-swizzled.
    const int srow = t >> 3;                      // 0..31 (+32*i)
    const int sq   = (t & 7) ^ (srow & 7);        // swizzled source col-quad
    const int wofs = (t & 192) * 16;              // wave-uniform segment in round

    float4 a0 = {0,0,0,0}, a1 = {0,0,0,0};
    float l0 = 0.f, l1 = 0.f;                     // linear term (ksub==0 lanes)

    const int qxb = rs & 7;

    // prologue: chunk 0 -> buf 0
    #pragma unroll
    for (int i = 0; i < 4; ++i)
        gload_lds16(xb + (size_t)(srow + 32 * i) * N_ + 0 * NC + sq * 4,
                    (float*)(xT[0] + i * 4096 + wofs));
    __syncthreads();

    for (int nc = 0; nc < NCHUNKS; ++nc) {
        // issue next chunk's loads (async, no wait) into the other buffer
        if (nc + 1 < NCHUNKS) {
            #pragma unroll
            for (int i = 0; i < 4; ++i)
                gload_lds16(xb + (size_t)(srow + 32 * i) * N_ + (nc + 1) * NC + sq * 4,
                            (float*)(xT[(nc + 1) & 1] + i * 4096 + wofs));
        }

        // compute current chunk
        const unsigned char* const xr0 = xT[nc & 1] + rs * 128;
        #pragma unroll
        for (int q = 0; q < NC / 4; ++q) {
            const int qoff = ((q ^ qxb) << 4);
            const float4 x0 = *(const float4*)(xr0 +           qoff);
            const float4 x1 = *(const float4*)(xr0 + 64 * 128 + qoff);
            const int n0 = nc * NC + q * 4;
            const float4 v0 = *(const float4*)&vL[n0 + 0][ksub * 4];
            const float4 v1 = *(const float4*)&vL[n0 + 1][ksub * 4];
            const float4 v2 = *(const float4*)&vL[n0 + 2][ksub * 4];
            const float4 v3 = *(const float4*)&vL[n0 + 3][ksub * 4];

            a0.x += x0.x*v0.x + x0.y*v1.x + x0.z*v2.x + x0.w*v3.x;
            a0.y += x0.x*v0.y + x0.y*v1.y + x0.z*v2.y + x0.w*v3.y;
            a0.z += x0.x*v0.z + x0.y*v1.z + x0.z*v2.z + x0.w*v3.z;
            a0.w += x0.x*v0.w + x0.y*v1.w + x0.z*v2.w + x0.w*v3.w;

            a1.x += x1.x*v0.x + x1.y*v1.x + x1.z*v2.x + x1.w*v3.x;
            a1.y += x1.x*v0.y + x1.y*v1.y + x1.z*v2.y + x1.w*v3.y;
            a1.z += x1.x*v0.z + x1.y*v1.z + x1.z*v2.z + x1.w*v3.z;
            a1.w += x1.x*v0.w + x1.y*v1.w + x1.z*v2.w + x1.w*v3.w;

            if (ksub == 0) {
                const float4 wq = *(const float4*)&wL[n0];
                l0 += x0.x*wq.x + x0.y*wq.y + x0.z*wq.z + x0.w*wq.w;
                l1 += x1.x*wq.x + x1.y*wq.y + x1.z*wq.z + x1.w*wq.w;
            }
        }
        __syncthreads();   // drains vmcnt(0): next tile ready, buffers safe
    }

    // xv writes: 2 rows x float4, coalesced (1 KB contiguous per wave per row-set)
    {
        float* base = xv + ((size_t)b * M_ + m0 + rs) * K_ + ksub * 4;
        *(float4*)(base +  0 * K_) = a0;
        *(float4*)(base + 64 * K_) = a1;
    }

    // sv: local row-sum then butterfly over rs bits (4,8,16,32)
    float4 s = {a0.x + a1.x, a0.y + a1.y, a0.z + a1.z, a0.w + a1.w};
    #pragma unroll
    for (int off = 4; off < 64; off <<= 1) {
        s.x += __shfl_xor(s.x, off);
        s.y += __shfl_xor(s.y, off);
        s.z += __shfl_xor(s.z, off);
        s.w += __shfl_xor(s.w, off);
    }

    // epilogue reductions reuse xT (all compute finished at loop-end barrier)
    float* lred = (float*)xT[0];             // 128 floats
    float* red  = (float*)(xT[0] + 1024);    // 4 waves x 16 floats
    const int wave = t >> 6;
    if ((t & 63) < 4)
        *(float4*)(red + wave * 16 + ksub * 4) = s;
    if (ksub == 0) {
        lred[rs]      = l0;
        lred[rs + 64] = l1;
    }
    __syncthreads();
    if (t < ROWS)
        out[(size_t)b * M_ + m0 + t] = lred[t] + bias[0];
    if (t < 16)
        svpart[(size_t)blk * 16 + t] = red[t] + red[16 + t] + red[32 + t] + red[48 + t];
}

// ---------------- Pass 2 ----------------
// grid = B_*2 blocks, 256 threads; thread per row.
__global__ __launch_bounds__(256) void fm_pass2(
    const float* __restrict__ xv, const float* __restrict__ svpart,
    float* __restrict__ out)
{
    const int t = threadIdx.x;
    const int blk = blockIdx.x;
    const int b = blk >> 1;
    const int m = (blk & 1) * 256 + t;
    __shared__ __align__(16) float svL[16];
    if (t < 16) {
        float s = 0.f;
        #pragma unroll
        for (int j = 0; j < 4; ++j) s += svpart[((size_t)b * 4 + j) * 16 + t];
        svL[t] = s;
    }
    __syncthreads();

    const float4* xvp = (const float4*)(xv + ((size_t)b * M_ + m) * K_);
    float4 a0 = xvp[0], a1 = xvp[1], a2 = xvp[2], a3 = xvp[3];
    const float4* s4 = (const float4*)svL;
    float4 s0 = s4[0], s1 = s4[1], s2 = s4[2], s3 = s4[3];

    float rs = a0.x * s0.x + a0.y * s0.y + a0.z * s0.z + a0.w * s0.w
             + a1.x * s1.x + a1.y * s1.y + a1.z * s1.z + a1.w * s1.w
             + a2.x * s2.x + a2.y * s2.y + a2.z * s2.z + a2.w * s2.w
             + a3.x * s3.x + a3.y * s3.y + a3.z * s3.z + a3.w * s3.w;
    float dg = a0.x * a0.x + a0.y * a0.y + a0.z * a0.z + a0.w * a0.w
             + a1.x * a1.x + a1.y * a1.y + a1.z * a1.z + a1.w * a1.w
             + a2.x * a2.x + a2.y * a2.y + a2.z * a2.z + a2.w * a2.w
             + a3.x * a3.x + a3.y * a3.y + a3.z * a3.z + a3.w * a3.w;

    const size_t o = (size_t)b * M_ + m;
    out[o] = out[o] + 0.5f * (rs - dg);
}

extern "C" void kernel_launch(void* const* d_in, const int* in_sizes, int n_in,
                              void* d_out, int out_size, void* d_ws, size_t ws_size,
                              hipStream_t stream) {
    const float* x    = (const float*)d_in[0];
    const float* w    = (const float*)d_in[1];
    const float* bias = (const float*)d_in[2];
    const float* v    = (const float*)d_in[3];
    float* out = (float*)d_out;

    float* xv     = (float*)d_ws;                 // B*M*K floats = 8 MiB
    float* svpart = xv + (size_t)B_ * M_ * K_;    // 1024*16 floats

    fm_pass1<<<dim3(B_ * (M_ / ROWS)), dim3(256), 0, stream>>>(x, w, bias, v, xv, svpart, out);
    fm_pass2<<<dim3(B_ * 2), dim3(256), 0, stream>>>(xv, svpart, out);
}

// Round 6
// 44.597 us; speedup vs baseline: 13.2617x; 1.0178x over previous
//
#include <hip/hip_runtime.h>

#define B_ 256
#define M_ 512
#define N_ 256
#define K_ 16
#define TROWS 128            // rows per LDS tile
#define NC 32                // n-cols per chunk
#define NCHUNKS (N_ / NC)    // 8
#define NPHASE (2 * NCHUNKS) // 16 phases: 2 tiles x 8 chunks

// direct global->LDS, 16B per lane, no VGPR staging
__device__ __forceinline__ void gload_lds16(const float* g, float* l) {
    __builtin_amdgcn_global_load_lds(
        (const __attribute__((address_space(1))) void*)g,
        (__attribute__((address_space(3))) void*)l,
        16, 0, 0);
}

// ---------------- Pass 1 ----------------
// grid = B_*2 = 512 blocks (2 blocks/CU, all resident), 256 threads.
// Block owns 256 rows, processed as two sequential 128-row tiles with the
// double-buffer pipelined across the boundary (16 linear phases).
// Thread t = (rs = t>>2 in 0..63, ksub = t&3): rows {rs, rs+64} of the
// current tile, k-quad [ksub*4, ksub*4+4).
__global__ __launch_bounds__(256) void fm_pass1(
    const float* __restrict__ x, const float* __restrict__ w,
    const float* __restrict__ bias, const float* __restrict__ v,
    float* __restrict__ xv, float* __restrict__ svpart, float* __restrict__ out)
{
    __shared__ __align__(16) float vL[N_][K_];                    // 16 KiB
    __shared__ __align__(16) float wL[N_];                        // 1 KiB
    __shared__ __align__(16) unsigned char xT[2][TROWS * NC * 4]; // 2 x 16 KiB
    __shared__ __align__(16) float red[64];                       // sv partials

    const int t    = threadIdx.x;
    const int rs   = t >> 2;        // 0..63
    const int ksub = t & 3;
    const int blk  = blockIdx.x;
    const int b    = blk >> 1;
    const int m0   = (blk & 1) * 256;

    // stage v (4096 floats) and w (256 floats) once
    {
        const float4* v4 = (const float4*)v;
        float4* vL4 = (float4*)&vL[0][0];
        #pragma unroll
        for (int i = 0; i < 4; ++i) vL4[t + 256 * i] = v4[t + 256 * i];
        wL[t] = w[t];
    }

    const float* xb = x + ((size_t)b * M_ + m0) * N_;

    // staging: round i covers tile-rows 32i..32i+31, 128 B per row.
    // LDS dest linear (forced by global_load_lds); source col-quad pre-swizzled
    // with the same XOR used on the read side.
    const int srow = t >> 3;                      // 0..31 (+32*i)
    const int sq   = (t & 7) ^ (srow & 7);        // swizzled source col-quad
    const int wofs = (t & 192) * 16;              // wave-uniform segment in round

    float4 a0 = {0,0,0,0}, a1 = {0,0,0,0};
    float l0 = 0.f, l1 = 0.f;                     // linear term (ksub==0 lanes)
    float4 s = {0,0,0,0};                         // sv partial across both tiles

    const int qxb = rs & 7;
    const float bias0 = bias[0];

    // prologue: phase 0 (tile 0, cols 0..31) -> buf 0
    #pragma unroll
    for (int i = 0; i < 4; ++i)
        gload_lds16(xb + (size_t)(srow + 32 * i) * N_ + sq * 4,
                    (float*)(xT[0] + i * 4096 + wofs));
    __syncthreads();

    for (int half = 0; half < 2; ++half) {
        for (int nc = 0; nc < NCHUNKS; ++nc) {
            const int p = half * NCHUNKS + nc;
            // issue next phase's loads (async) into the other buffer
            if (p + 1 < NPHASE) {
                const int nrb  = ((p + 1) >> 3) << 7;      // 0 or 128
                const int ncol = ((p + 1) & 7) * NC;
                #pragma unroll
                for (int i = 0; i < 4; ++i)
                    gload_lds16(xb + (size_t)(nrb + srow + 32 * i) * N_ + ncol + sq * 4,
                                (float*)(xT[(p + 1) & 1] + i * 4096 + wofs));
            }

            // compute current chunk
            const unsigned char* const xr0 = xT[p & 1] + rs * 128;
            #pragma unroll
            for (int q = 0; q < NC / 4; ++q) {
                const int qoff = ((q ^ qxb) << 4);
                const float4 x0 = *(const float4*)(xr0 +           qoff);
                const float4 x1 = *(const float4*)(xr0 + 64 * 128 + qoff);
                const int n0 = nc * NC + q * 4;
                const float4 v0 = *(const float4*)&vL[n0 + 0][ksub * 4];
                const float4 v1 = *(const float4*)&vL[n0 + 1][ksub * 4];
                const float4 v2 = *(const float4*)&vL[n0 + 2][ksub * 4];
                const float4 v3 = *(const float4*)&vL[n0 + 3][ksub * 4];

                a0.x += x0.x*v0.x + x0.y*v1.x + x0.z*v2.x + x0.w*v3.x;
                a0.y += x0.x*v0.y + x0.y*v1.y + x0.z*v2.y + x0.w*v3.y;
                a0.z += x0.x*v0.z + x0.y*v1.z + x0.z*v2.z + x0.w*v3.z;
                a0.w += x0.x*v0.w + x0.y*v1.w + x0.z*v2.w + x0.w*v3.w;

                a1.x += x1.x*v0.x + x1.y*v1.x + x1.z*v2.x + x1.w*v3.x;
                a1.y += x1.x*v0.y + x1.y*v1.y + x1.z*v2.y + x1.w*v3.y;
                a1.z += x1.x*v0.z + x1.y*v1.z + x1.z*v2.z + x1.w*v3.z;
                a1.w += x1.x*v0.w + x1.y*v1.w + x1.z*v2.w + x1.w*v3.w;

                if (ksub == 0) {
                    const float4 wq = *(const float4*)&wL[n0];
                    l0 += x0.x*wq.x + x0.y*wq.y + x0.z*wq.z + x0.w*wq.w;
                    l1 += x1.x*wq.x + x1.y*wq.y + x1.z*wq.z + x1.w*wq.w;
                }
            }
            __syncthreads();   // drains vmcnt: next tile ready, buffers safe
        }

        // flush this 128-row tile: xv + linear term; fold into sv partial
        {
            float* base = xv + ((size_t)b * M_ + m0 + half * TROWS + rs) * K_ + ksub * 4;
            *(float4*)(base +  0 * K_) = a0;
            *(float4*)(base + 64 * K_) = a1;
            if (ksub == 0) {
                out[(size_t)b * M_ + m0 + half * TROWS + rs]      = l0 + bias0;
                out[(size_t)b * M_ + m0 + half * TROWS + rs + 64] = l1 + bias0;
            }
            s.x += a0.x + a1.x; s.y += a0.y + a1.y;
            s.z += a0.z + a1.z; s.w += a0.w + a1.w;
            a0 = {0,0,0,0}; a1 = {0,0,0,0};
            l0 = 0.f; l1 = 0.f;
        }
    }

    // sv: butterfly over rs bits (4,8,16,32), combine 4 waves via small LDS
    #pragma unroll
    for (int off = 4; off < 64; off <<= 1) {
        s.x += __shfl_xor(s.x, off);
        s.y += __shfl_xor(s.y, off);
        s.z += __shfl_xor(s.z, off);
        s.w += __shfl_xor(s.w, off);
    }
    const int wave = t >> 6;
    if ((t & 63) < 4)
        *(float4*)(red + wave * 16 + ksub * 4) = s;
    __syncthreads();
    if (t < 16)
        svpart[(size_t)blk * 16 + t] = red[t] + red[16 + t] + red[32 + t] + red[48 + t];
}

// ---------------- Pass 2 ----------------
// grid = B_*2 blocks, 256 threads; thread per row.
__global__ __launch_bounds__(256) void fm_pass2(
    const float* __restrict__ xv, const float* __restrict__ svpart,
    float* __restrict__ out)
{
    const int t = threadIdx.x;
    const int blk = blockIdx.x;
    const int b = blk >> 1;
    const int m = (blk & 1) * 256 + t;
    __shared__ __align__(16) float svL[16];
    if (t < 16)
        svL[t] = svpart[(size_t)(b * 2 + 0) * 16 + t] + svpart[(size_t)(b * 2 + 1) * 16 + t];
    __syncthreads();

    const float4* xvp = (const float4*)(xv + ((size_t)b * M_ + m) * K_);
    float4 a0 = xvp[0], a1 = xvp[1], a2 = xvp[2], a3 = xvp[3];
    const float4* s4 = (const float4*)svL;
    float4 s0 = s4[0], s1 = s4[1], s2 = s4[2], s3 = s4[3];

    float rs = a0.x * s0.x + a0.y * s0.y + a0.z * s0.z + a0.w * s0.w
             + a1.x * s1.x + a1.y * s1.y + a1.z * s1.z + a1.w * s1.w
             + a2.x * s2.x + a2.y * s2.y + a2.z * s2.z + a2.w * s2.w
             + a3.x * s3.x + a3.y * s3.y + a3.z * s3.z + a3.w * s3.w;
    float dg = a0.x * a0.x + a0.y * a0.y + a0.z * a0.z + a0.w * a0.w
             + a1.x * a1.x + a1.y * a1.y + a1.z * a1.z + a1.w * a1.w
             + a2.x * a2.x + a2.y * a2.y + a2.z * a2.z + a2.w * a2.w
             + a3.x * a3.x + a3.y * a3.y + a3.z * a3.z + a3.w * a3.w;

    const size_t o = (size_t)b * M_ + m;
    out[o] = out[o] + 0.5f * (rs - dg);
}

extern "C" void kernel_launch(void* const* d_in, const int* in_sizes, int n_in,
                              void* d_out, int out_size, void* d_ws, size_t ws_size,
                              hipStream_t stream) {
    const float* x    = (const float*)d_in[0];
    const float* w    = (const float*)d_in[1];
    const float* bias = (const float*)d_in[2];
    const float* v    = (const float*)d_in[3];
    float* out = (float*)d_out;

    float* xv     = (float*)d_ws;                 // B*M*K floats = 8 MiB
    float* svpart = xv + (size_t)B_ * M_ * K_;    // 512*16 floats

    fm_pass1<<<dim3(B_ * 2), dim3(256), 0, stream>>>(x, w, bias, v, xv, svpart, out);
    fm_pass2<<<dim3(B_ * 2), dim3(256), 0, stream>>>(xv, svpart, out);
}

// Round 7
// 43.675 us; speedup vs baseline: 13.5416x; 1.0211x over previous
//
#include <hip/hip_runtime.h>

#define B_ 256
#define M_ 512
#define N_ 256
#define K_ 16
#define TROWS 256            // rows per block tile
#define NC 16                // n-cols per chunk
#define NPHASE (N_ / NC)     // 16

// direct global->LDS, 16B per lane, no VGPR staging
__device__ __forceinline__ void gload_lds16(const float* g, float* l) {
    __builtin_amdgcn_global_load_lds(
        (const __attribute__((address_space(1))) void*)g,
        (__attribute__((address_space(3))) void*)l,
        16, 0, 0);
}

// ---------------- Pass 1 ----------------
// grid = B_*2 = 512 blocks, 256 threads. Block owns 256 rows; chunk = 16 cols.
// Thread t = (rs = t>>2 in 0..63, ksub = t&3): owns rows {rs, rs+64, rs+128,
// rs+192} and k-quad [ksub*4, ksub*4+4). Per q-iter: 8 LDS reads -> 64 FMAs.
__global__ __launch_bounds__(256) void fm_pass1(
    const float* __restrict__ x, const float* __restrict__ w,
    const float* __restrict__ bias, const float* __restrict__ v,
    float* __restrict__ xv, float* __restrict__ svpart, float* __restrict__ out)
{
    __shared__ __align__(16) float vL[N_][K_];                   // 16 KiB
    __shared__ __align__(16) float wL[N_];                       // 1 KiB
    __shared__ __align__(16) unsigned char xT[2][TROWS * NC * 4];// 2 x 16 KiB
    __shared__ __align__(16) float red[64];                      // sv partials

    const int t    = threadIdx.x;
    const int rs   = t >> 2;        // 0..63
    const int ksub = t & 3;
    const int blk  = blockIdx.x;
    const int b    = blk >> 1;
    const int m0   = (blk & 1) * TROWS;

    // stage v (4096 floats) and w (256 floats) once
    {
        const float4* v4 = (const float4*)v;
        float4* vL4 = (float4*)&vL[0][0];
        #pragma unroll
        for (int i = 0; i < 4; ++i) vL4[t + 256 * i] = v4[t + 256 * i];
        wL[t] = w[t];
    }

    const float* xb = x + ((size_t)b * M_ + m0) * N_;

    // staging: round i covers rows 64i..64i+63, 64 B per row (4 lanes x 16 B).
    // LDS dest is linear (lane byte = t*16 within round); the source col-quad
    // is pre-swizzled with the same XOR used on the read side.
    const int srow = t >> 2;                       // == rs
    const int sq   = (t & 3) ^ ((srow >> 1) & 3);  // swizzled source col-quad
    const int wofs = (t & 192) * 16;               // wave-uniform segment base

    float4 a0 = {0,0,0,0}, a1 = {0,0,0,0}, a2 = {0,0,0,0}, a3 = {0,0,0,0};
    float l0 = 0.f, l1 = 0.f, l2 = 0.f, l3 = 0.f;  // linear term (ksub==0)

    const int qx = (rs >> 1) & 3;
    const unsigned char* const xr0 = xT[0] + rs * 64;   // +buf sel via p&1 below
    const float bias0 = bias[0];

    // prologue: phase 0 (cols 0..15) -> buf 0
    #pragma unroll
    for (int i = 0; i < 4; ++i)
        gload_lds16(xb + (size_t)(srow + 64 * i) * N_ + sq * 4,
                    (float*)(xT[0] + i * 4096 + wofs));
    __syncthreads();

    for (int p = 0; p < NPHASE; ++p) {
        // issue next phase's loads (async) into the other buffer
        if (p + 1 < NPHASE) {
            const float* src = xb + (p + 1) * NC + sq * 4;
            unsigned char* dst = xT[(p + 1) & 1];
            #pragma unroll
            for (int i = 0; i < 4; ++i)
                gload_lds16(src + (size_t)(srow + 64 * i) * N_,
                            (float*)(dst + i * 4096 + wofs));
        }

        // compute current chunk (16 cols = 4 q-iters)
        const unsigned char* const xr = xr0 + ((p & 1) ? (TROWS * NC * 4) : 0);
        #pragma unroll
        for (int q = 0; q < NC / 4; ++q) {
            const int qoff = ((q ^ qx) << 4);
            const float4 x0 = *(const float4*)(xr +        qoff);
            const float4 x1 = *(const float4*)(xr + 4096 + qoff);
            const float4 x2 = *(const float4*)(xr + 8192 + qoff);
            const float4 x3 = *(const float4*)(xr + 12288 + qoff);
            const int n0 = p * NC + q * 4;
            const float4 v0 = *(const float4*)&vL[n0 + 0][ksub * 4];
            const float4 v1 = *(const float4*)&vL[n0 + 1][ksub * 4];
            const float4 v2 = *(const float4*)&vL[n0 + 2][ksub * 4];
            const float4 v3 = *(const float4*)&vL[n0 + 3][ksub * 4];

            a0.x += x0.x*v0.x + x0.y*v1.x + x0.z*v2.x + x0.w*v3.x;
            a0.y += x0.x*v0.y + x0.y*v1.y + x0.z*v2.y + x0.w*v3.y;
            a0.z += x0.x*v0.z + x0.y*v1.z + x0.z*v2.z + x0.w*v3.z;
            a0.w += x0.x*v0.w + x0.y*v1.w + x0.z*v2.w + x0.w*v3.w;

            a1.x += x1.x*v0.x + x1.y*v1.x + x1.z*v2.x + x1.w*v3.x;
            a1.y += x1.x*v0.y + x1.y*v1.y + x1.z*v2.y + x1.w*v3.y;
            a1.z += x1.x*v0.z + x1.y*v1.z + x1.z*v2.z + x1.w*v3.z;
            a1.w += x1.x*v0.w + x1.y*v1.w + x1.z*v2.w + x1.w*v3.w;

            a2.x += x2.x*v0.x + x2.y*v1.x + x2.z*v2.x + x2.w*v3.x;
            a2.y += x2.x*v0.y + x2.y*v1.y + x2.z*v2.y + x2.w*v3.y;
            a2.z += x2.x*v0.z + x2.y*v1.z + x2.z*v2.z + x2.w*v3.z;
            a2.w += x2.x*v0.w + x2.y*v1.w + x2.z*v2.w + x2.w*v3.w;

            a3.x += x3.x*v0.x + x3.y*v1.x + x3.z*v2.x + x3.w*v3.x;
            a3.y += x3.x*v0.y + x3.y*v1.y + x3.z*v2.y + x3.w*v3.y;
            a3.z += x3.x*v0.z + x3.y*v1.z + x3.z*v2.z + x3.w*v3.z;
            a3.w += x3.x*v0.w + x3.y*v1.w + x3.z*v2.w + x3.w*v3.w;

            if (ksub == 0) {
                const float4 wq = *(const float4*)&wL[n0];
                l0 += x0.x*wq.x + x0.y*wq.y + x0.z*wq.z + x0.w*wq.w;
                l1 += x1.x*wq.x + x1.y*wq.y + x1.z*wq.z + x1.w*wq.w;
                l2 += x2.x*wq.x + x2.y*wq.y + x2.z*wq.z + x2.w*wq.w;
                l3 += x3.x*wq.x + x3.y*wq.y + x3.z*wq.z + x3.w*wq.w;
            }
        }
        __syncthreads();   // drains vmcnt: next tile ready, buffers safe
    }

    // xv writes: 4 rows x float4, coalesced (1 KB contiguous per wave per row-set)
    {
        float* base = xv + ((size_t)b * M_ + m0 + rs) * K_ + ksub * 4;
        *(float4*)(base +   0 * K_) = a0;
        *(float4*)(base +  64 * K_) = a1;
        *(float4*)(base + 128 * K_) = a2;
        *(float4*)(base + 192 * K_) = a3;
    }
    if (ksub == 0) {
        float* ob = out + (size_t)b * M_ + m0 + rs;
        ob[0]   = l0 + bias0;
        ob[64]  = l1 + bias0;
        ob[128] = l2 + bias0;
        ob[192] = l3 + bias0;
    }

    // sv: local 4-row sum, butterfly over rs bits (4,8,16,32), cross-wave via LDS
    float4 s = {a0.x + a1.x + a2.x + a3.x,
                a0.y + a1.y + a2.y + a3.y,
                a0.z + a1.z + a2.z + a3.z,
                a0.w + a1.w + a2.w + a3.w};
    #pragma unroll
    for (int off = 4; off < 64; off <<= 1) {
        s.x += __shfl_xor(s.x, off);
        s.y += __shfl_xor(s.y, off);
        s.z += __shfl_xor(s.z, off);
        s.w += __shfl_xor(s.w, off);
    }
    const int wave = t >> 6;
    if ((t & 63) < 4)
        *(float4*)(red + wave * 16 + ksub * 4) = s;
    __syncthreads();
    if (t < 16)
        svpart[(size_t)blk * 16 + t] = red[t] + red[16 + t] + red[32 + t] + red[48 + t];
}

// ---------------- Pass 2 ----------------
// grid = B_*2 blocks, 256 threads; thread per row.
__global__ __launch_bounds__(256) void fm_pass2(
    const float* __restrict__ xv, const float* __restrict__ svpart,
    float* __restrict__ out)
{
    const int t = threadIdx.x;
    const int blk = blockIdx.x;
    const int b = blk >> 1;
    const int m = (blk & 1) * 256 + t;
    __shared__ __align__(16) float svL[16];
    if (t < 16)
        svL[t] = svpart[(size_t)(b * 2 + 0) * 16 + t] + svpart[(size_t)(b * 2 + 1) * 16 + t];
    __syncthreads();

    const float4* xvp = (const float4*)(xv + ((size_t)b * M_ + m) * K_);
    float4 a0 = xvp[0], a1 = xvp[1], a2 = xvp[2], a3 = xvp[3];
    const float4* s4 = (const float4*)svL;
    float4 s0 = s4[0], s1 = s4[1], s2 = s4[2], s3 = s4[3];

    float rs = a0.x * s0.x + a0.y * s0.y + a0.z * s0.z + a0.w * s0.w
             + a1.x * s1.x + a1.y * s1.y + a1.z * s1.z + a1.w * s1.w
             + a2.x * s2.x + a2.y * s2.y + a2.z * s2.z + a2.w * s2.w
             + a3.x * s3.x + a3.y * s3.y + a3.z * s3.z + a3.w * s3.w;
    float dg = a0.x * a0.x + a0.y * a0.y + a0.z * a0.z + a0.w * a0.w
             + a1.x * a1.x + a1.y * a1.y + a1.z * a1.z + a1.w * a1.w
             + a2.x * a2.x + a2.y * a2.y + a2.z * a2.z + a2.w * a2.w
             + a3.x * a3.x + a3.y * a3.y + a3.z * a3.z + a3.w * a3.w;

    const size_t o = (size_t)b * M_ + m;
    out[o] = out[o] + 0.5f * (rs - dg);
}

extern "C" void kernel_launch(void* const* d_in, const int* in_sizes, int n_in,
                              void* d_out, int out_size, void* d_ws, size_t ws_size,
                              hipStream_t stream) {
    const float* x    = (const float*)d_in[0];
    const float* w    = (const float*)d_in[1];
    const float* bias = (const float*)d_in[2];
    const float* v    = (const float*)d_in[3];
    float* out = (float*)d_out;

    float* xv     = (float*)d_ws;                 // B*M*K floats = 8 MiB
    float* svpart = xv + (size_t)B_ * M_ * K_;    // 512*16 floats

    fm_pass1<<<dim3(B_ * 2), dim3(256), 0, stream>>>(x, w, bias, v, xv, svpart, out);
    fm_pass2<<<dim3(B_ * 2), dim3(256), 0, stream>>>(xv, svpart, out);
}